// Round 5
// baseline (72.808 us; speedup 1.0000x reference)
//
#include <hip/hip_runtime.h>
#include <hip/hip_bf16.h>
#include <cstddef>
#include <cstdint>

#define EMB   256
#define TWOD  512
#define NREL  128
#define BATCH 4096
#define LOG_SQRT_2PI 0.9189385332046727f

typedef __bf16          bf16x2  __attribute__((ext_vector_type(2)));
typedef __bf16          bf16x8  __attribute__((ext_vector_type(8)));
typedef unsigned short  u16x8   __attribute__((ext_vector_type(8)));
typedef float           f32x4   __attribute__((ext_vector_type(4)));

__device__ __forceinline__ unsigned short f2bf(float f) {
    unsigned u = __builtin_bit_cast(unsigned, f);
    u = (u + 0x7FFFu + ((u >> 16) & 1u)) >> 16;
    return (unsigned short)u;
}

// Hardware packed f32->bf16 (RNE) when available; manual RNE fallback.
__device__ __forceinline__ bf16x2 cvt2(float a, float b) {
#if __has_builtin(__builtin_amdgcn_cvt_pk_bf16_f32)
    return __builtin_amdgcn_cvt_pk_bf16_f32(a, b);
#else
    bf16x2 r;
    r[0] = __builtin_bit_cast(__bf16, f2bf(a));
    r[1] = __builtin_bit_cast(__bf16, f2bf(b));
    return r;
#endif
}

__device__ __forceinline__ float frcp(float x) {
#if __has_builtin(__builtin_amdgcn_rcpf)
    return __builtin_amdgcn_rcpf(x);
#else
    return 1.0f / x;
#endif
}

__device__ __forceinline__ bf16x8 pack8(float4 a, float4 b) {
    const bf16x2 p0 = cvt2(a.x, a.y), p1 = cvt2(a.z, a.w);
    const bf16x2 p2 = cvt2(b.x, b.y), p3 = cvt2(b.z, b.w);
    bf16x8 r;
    r[0] = p0[0]; r[1] = p0[1]; r[2] = p1[0]; r[3] = p1[1];
    r[4] = p2[0]; r[5] = p2[1]; r[6] = p3[0]; r[7] = p3[1];
    return r;
}

// ---------------------------------------------------------------------------
// K1: (mu, sigma, prior) -> Wi bf16 interleaved [k8][r][c:8 | a:8] (256 KB),
// cst[r] = sum_k e + 512*prior.  128 blocks x 64 thr, one k8-oct per thread,
// 32 B contiguous store, wave-reduce for cst. No LDS, no atomics.
// ---------------------------------------------------------------------------
__global__ __launch_bounds__(64) void nb_prep(
    const float* __restrict__ mus, const float* __restrict__ sigmas,
    const float* __restrict__ priors,
    unsigned short* __restrict__ Wi, float* __restrict__ cst)
{
    const int r  = blockIdx.x;
    const int k8 = threadIdx.x;          // 0..63
    const float* mp = mus    + (size_t)r * TWOD + k8 * 8;
    const float* sp = sigmas + (size_t)r * TWOD + k8 * 8;
    const float4 m0 = *(const float4*)mp,  m1 = *(const float4*)(mp + 4);
    const float4 s0 = *(const float4*)sp,  s1 = *(const float4*)(sp + 4);

    const float mu[8] = {m0.x, m0.y, m0.z, m0.w, m1.x, m1.y, m1.z, m1.w};
    const float sg[8] = {s0.x, s0.y, s0.z, s0.w, s1.x, s1.y, s1.z, s1.w};

    float cv[8], av[8], esum = 0.0f;
    #pragma unroll
    for (int i = 0; i < 8; i++) {
        const float inv2 = frcp(sg[i] * sg[i]);
        cv[i] = mu[i] * inv2;
        av[i] = -0.5f * inv2;
        esum += -0.5f * mu[i] * mu[i] * inv2 - __logf(sg[i]) - LOG_SQRT_2PI;
    }
    bf16x8 pc, pa;
    #pragma unroll
    for (int i = 0; i < 4; i++) {
        const bf16x2 qc = cvt2(cv[2 * i], cv[2 * i + 1]);
        const bf16x2 qa = cvt2(av[2 * i], av[2 * i + 1]);
        pc[2 * i] = qc[0]; pc[2 * i + 1] = qc[1];
        pa[2 * i] = qa[0]; pa[2 * i + 1] = qa[1];
    }
    unsigned short* w = Wi + (size_t)k8 * (NREL * 16) + r * 16;
    *(u16x8*)w       = __builtin_bit_cast(u16x8, pc);
    *(u16x8*)(w + 8) = __builtin_bit_cast(u16x8, pa);

    #pragma unroll
    for (int off = 32; off >= 1; off >>= 1)
        esum += __shfl_down(esum, off, 64);
    if (k8 == 0) cst[r] = esum + priors[r] * (float)TWOD;
}

// ---------------------------------------------------------------------------
// K2: barrier-free, LDS-free fused MFMA kernel.
//   out[b,r] = sum_k c[r,k]*x[b,k] + a[r,k]*x[b,k]^2 + cst[r]
// Grid 256 (1/CU), 4 waves, BM=16 rows, full K. Wave owns r-strip
// [wv*32, wv*32+32) -> B private, zero barriers, global->VGPR B loads
// (16B/lane, L2-reused), compiler pipelines with fine-grained vmcnt.
// A-frags (x, x^2) packed via hardware cvt_pk_bf16. 4 independent acc chains.
// ---------------------------------------------------------------------------
__global__ __launch_bounds__(256, 1) void nb_fused(
    const float* __restrict__ sbjs, const float* __restrict__ objs,
    const unsigned short* __restrict__ Wi,
    const float* __restrict__ cst, float* __restrict__ out)
{
    const int tid  = threadIdx.x;
    const int wv   = tid >> 6;
    const int lane = tid & 63;
    const int m16  = lane & 15;
    const int quad = lane >> 4;
    const int b0   = blockIdx.x * 16;
    const int row  = b0 + m16;

    // prefetch per-lane constants (latency hides under prologue/K-loop)
    const float ca0 = cst[wv * 32 + m16];
    const float ca1 = cst[wv * 32 + 16 + m16];

    // ---- preload all A-frags: x and x^2, hw-packed bf16 ----
    bf16x8 ax[16], ax2[16];
    #pragma unroll
    for (int fi = 0; fi < 16; fi++) {
        const int col = fi * 32 + quad * 8;          // compile-time per fi
        const float* p = (col < EMB)
            ? (sbjs + (size_t)row * EMB + col)
            : (objs + (size_t)row * EMB + (col - EMB));
        const float4 v0 = *(const float4*)p;
        const float4 v1 = *(const float4*)(p + 4);
        ax[fi] = pack8(v0, v1);
        const float4 q0 = {v0.x * v0.x, v0.y * v0.y, v0.z * v0.z, v0.w * v0.w};
        const float4 q1 = {v1.x * v1.x, v1.y * v1.y, v1.z * v1.z, v1.w * v1.w};
        ax2[fi] = pack8(q0, q1);
    }

    f32x4 accc[2], acca[2];
    accc[0] = (f32x4)0.0f; accc[1] = (f32x4)0.0f;
    acca[0] = (f32x4)0.0f; acca[1] = (f32x4)0.0f;

    // ---- K loop: 16 frags x (2 strips x 2 tensors), no barriers ----
    const unsigned short* wbase = Wi + (size_t)quad * (NREL * 16)
                                     + (wv * 32 + m16) * 16;
    #pragma unroll
    for (int fi = 0; fi < 16; fi++) {
        const unsigned short* wp = wbase + (size_t)fi * 4 * (NREL * 16);
        const bf16x8 bc0 = *(const bf16x8*)(wp);
        const bf16x8 ba0 = *(const bf16x8*)(wp + 8);
        const bf16x8 bc1 = *(const bf16x8*)(wp + 256);   // nt=1: +16 r
        const bf16x8 ba1 = *(const bf16x8*)(wp + 264);
        accc[0] = __builtin_amdgcn_mfma_f32_16x16x32_bf16(ax [fi], bc0, accc[0], 0, 0, 0);
        acca[0] = __builtin_amdgcn_mfma_f32_16x16x32_bf16(ax2[fi], ba0, acca[0], 0, 0, 0);
        accc[1] = __builtin_amdgcn_mfma_f32_16x16x32_bf16(ax [fi], bc1, accc[1], 0, 0, 0);
        acca[1] = __builtin_amdgcn_mfma_f32_16x16x32_bf16(ax2[fi], ba1, acca[1], 0, 0, 0);
    }

    // ---- epilogue: C layout col(r)=lane&15, row(b)=quad*4+reg ----
    #pragma unroll
    for (int nt = 0; nt < 2; nt++) {
        const int r  = wv * 32 + nt * 16 + m16;
        const float ca = nt ? ca1 : ca0;
        #pragma unroll
        for (int reg = 0; reg < 4; reg++)
            out[(size_t)(b0 + quad * 4 + reg) * NREL + r] =
                accc[nt][reg] + acca[nt][reg] + ca;
    }
}

// ---------------------------------------------------------------------------
// Fallback: one thread per (b,r), direct fp32 evaluation.
// ---------------------------------------------------------------------------
__global__ __launch_bounds__(256) void nb_slow(
    const float* __restrict__ sbjs, const float* __restrict__ objs,
    const float* __restrict__ mus, const float* __restrict__ sigmas,
    const float* __restrict__ priors, float* __restrict__ out)
{
    const int idx = blockIdx.x * 256 + threadIdx.x;
    const int b = idx >> 7;
    const int r = idx & (NREL - 1);
    float acc = priors[r] * (float)TWOD;
    for (int k = 0; k < TWOD; k++) {
        const float x  = (k < EMB) ? sbjs[(size_t)b * EMB + k]
                                   : objs[(size_t)b * EMB + (k - EMB)];
        const float mu = mus[r * TWOD + k];
        const float s  = sigmas[r * TWOD + k];
        const float z  = (x - mu) / s;
        acc += -0.5f * z * z - logf(s) - LOG_SQRT_2PI;
    }
    out[idx] = acc;
}

extern "C" void kernel_launch(void* const* d_in, const int* in_sizes, int n_in,
                              void* d_out, int out_size, void* d_ws, size_t ws_size,
                              hipStream_t stream)
{
    const float* sbjs   = (const float*)d_in[0];
    const float* objs   = (const float*)d_in[1];
    const float* mus    = (const float*)d_in[2];
    const float* sigmas = (const float*)d_in[3];
    const float* priors = (const float*)d_in[4];
    float* out = (float*)d_out;

    char* ws = (char*)d_ws;
    const size_t o_w   = 0;                          // 256 KB interleaved W
    const size_t o_cst = 256 << 10;
    const size_t need  = o_cst + NREL * sizeof(float);

    if (ws_size >= need) {
        unsigned short* Wi = (unsigned short*)(ws + o_w);
        float* cst = (float*)(ws + o_cst);
        nb_prep<<<NREL, 64, 0, stream>>>(mus, sigmas, priors, Wi, cst);
        nb_fused<<<BATCH / 16, 256, 0, stream>>>(sbjs, objs, Wi, cst, out);
    } else {
        nb_slow<<<(BATCH * NREL) / 256, 256, 0, stream>>>(
            sbjs, objs, mus, sigmas, priors, out);
    }
}